// Round 1
// baseline (673.157 us; speedup 1.0000x reference)
//
#include <hip/hip_runtime.h>
#include <stdint.h>

#define NN 8192
#define FF 128
#define DD 4
#define BM 128
#define BN 128
#define BK 64
#define KSPLIT 8
#define KCHUNK (NN / KSPLIT)  // 1024

typedef __attribute__((ext_vector_type(8))) short bf16x8;
typedef __attribute__((ext_vector_type(4))) float f32x4;

__device__ __forceinline__ unsigned short f2bf(float f) {
  uint32_t u = __float_as_uint(f);
  u += 0x7fffu + ((u >> 16) & 1u);  // round-to-nearest-even
  return (unsigned short)(u >> 16);
}

__device__ __forceinline__ void gld_lds16(const void* g, void* l) {
  auto gp = reinterpret_cast<const uint32_t __attribute__((address_space(1)))*>(
      reinterpret_cast<uintptr_t>(g));
  auto lp = reinterpret_cast<uint32_t __attribute__((address_space(3)))*>(
      reinterpret_cast<uintptr_t>(l));
  __builtin_amdgcn_global_load_lds(gp, lp, 16, 0, 0);
}

// ---------------- adj fp32 -> bf16 ----------------
__global__ void cvt_adj(const float* __restrict__ a, unsigned short* __restrict__ o) {
  size_t i = ((size_t)blockIdx.x * 256 + threadIdx.x) * 8;
  float4 v0 = *(const float4*)(a + i);
  float4 v1 = *(const float4*)(a + i + 4);
  union { unsigned short us[8]; uint4 v; } p;
  p.us[0] = f2bf(v0.x); p.us[1] = f2bf(v0.y); p.us[2] = f2bf(v0.z); p.us[3] = f2bf(v0.w);
  p.us[4] = f2bf(v1.x); p.us[5] = f2bf(v1.y); p.us[6] = f2bf(v1.z); p.us[7] = f2bf(v1.w);
  *(uint4*)(o + i) = p.v;
}

// ---------------- in_feat [NN][FF] fp32 -> featT [FF][NN] bf16 ----------------
__global__ void cvt_feat(const float* __restrict__ x, unsigned short* __restrict__ xT) {
  __shared__ float tile[32][33];
  int m0 = blockIdx.x * 32;
  int n0 = blockIdx.y * 32;
  int tx = threadIdx.x & 31, ty = threadIdx.x >> 5;
#pragma unroll
  for (int r = 0; r < 4; ++r) {
    int mm = ty + r * 8;
    tile[mm][tx] = x[(size_t)(m0 + mm) * FF + n0 + tx];
  }
  __syncthreads();
#pragma unroll
  for (int r = 0; r < 4; ++r) {
    int nn = ty + r * 8;
    xT[(size_t)(n0 + nn) * NN + m0 + tx] = f2bf(tile[tx][nn]);
  }
}

// ---------------- GEMM: feat32[m][n] += sum_k adj_bf[m][k] * featT[n][k] ----------------
__global__ __launch_bounds__(256, 2) void gemm_hop(
    const unsigned short* __restrict__ adjb,
    const unsigned short* __restrict__ featT,
    float* __restrict__ feat32) {
  __shared__ unsigned short sA[BM * BK];  // 16 KB, XOR-swizzled chunks
  __shared__ unsigned short sB[BN * BK];  // 16 KB

  const int bx = blockIdx.x;
  const int mt = bx & 63;
  const int ks = bx >> 6;
  const int m0 = mt * BM;
  const int k0 = ks * KCHUNK;

  const int t = threadIdx.x;
  const int w = t >> 6;
  const int l = t & 63;

  // Staging plan: sA/sB are each 16 KB = 16 wave-instructions of 1 KB.
  // Wave w, inst j covers LDS bytes [w*4096 + j*1024, +1024).
  // Stored chunk c of row r holds GLOBAL chunk c ^ (r&7)  (conflict-free reads,
  // LDS side stays linear for global_load_lds).
  uint32_t offA[4], offB[4];
  unsigned short* ldsA[4];
  unsigned short* ldsB[4];
#pragma unroll
  for (int j = 0; j < 4; ++j) {
    uint32_t obase = (uint32_t)w * 4096u + (uint32_t)j * 1024u;
    uint32_t o = obase + (uint32_t)l * 16u;  // this lane's LDS byte
    uint32_t r = o >> 7;                     // row 0..127 (128 B rows)
    uint32_t c = (o >> 4) & 7u;              // stored 16B chunk in row
    uint32_t gc = c ^ (r & 7u);              // global chunk to fetch
    ldsA[j] = sA + (obase >> 1);             // wave-uniform base
    ldsB[j] = sB + (obase >> 1);
    offA[j] = (uint32_t)(m0 + r) * (uint32_t)NN + (uint32_t)k0 + gc * 8u;
    offB[j] = r * (uint32_t)NN + (uint32_t)k0 + gc * 8u;
  }

  f32x4 acc[4][4];
#pragma unroll
  for (int i = 0; i < 4; ++i)
#pragma unroll
    for (int j = 0; j < 4; ++j) acc[i][j] = (f32x4){0.f, 0.f, 0.f, 0.f};

  const int wm = w >> 1;  // 2x2 wave grid, each wave 64x64
  const int wn = w & 1;
  const int lr = l & 15;  // fragment row (A) / col (B)
  const int lq = l >> 4;  // quad

  for (int kt = 0; kt < KCHUNK; kt += BK) {
#pragma unroll
    for (int j = 0; j < 4; ++j) gld_lds16(adjb + offA[j], ldsA[j]);
#pragma unroll
    for (int j = 0; j < 4; ++j) gld_lds16(featT + offB[j], ldsB[j]);
#pragma unroll
    for (int j = 0; j < 4; ++j) { offA[j] += BK; offB[j] += BK; }
    __syncthreads();  // drains vmcnt -> DMA complete
#pragma unroll
    for (int kk = 0; kk < 2; ++kk) {
      bf16x8 af[4], bfr[4];
#pragma unroll
      for (int tm = 0; tm < 4; ++tm) {
        int row = wm * 64 + tm * 16 + lr;
        int ch = (kk * 4 + lq) ^ (row & 7);
        af[tm] = *(const bf16x8*)(sA + row * BK + ch * 8);
      }
#pragma unroll
      for (int tn = 0; tn < 4; ++tn) {
        int row = wn * 64 + tn * 16 + lr;
        int ch = (kk * 4 + lq) ^ (row & 7);
        bfr[tn] = *(const bf16x8*)(sB + row * BK + ch * 8);
      }
#pragma unroll
      for (int tm = 0; tm < 4; ++tm)
#pragma unroll
        for (int tn = 0; tn < 4; ++tn)
          acc[tm][tn] = __builtin_amdgcn_mfma_f32_16x16x32_bf16(
              af[tm], bfr[tn], acc[tm][tn], 0, 0, 0);
    }
    __syncthreads();
  }

  // epilogue: split-K partials -> atomic fp32
#pragma unroll
  for (int tm = 0; tm < 4; ++tm) {
#pragma unroll
    for (int tn = 0; tn < 4; ++tn) {
      int m = m0 + wm * 64 + tm * 16 + lq * 4;
      int n = wn * 64 + tn * 16 + lr;
#pragma unroll
      for (int r = 0; r < 4; ++r)
        atomicAdd(feat32 + (size_t)(m + r) * FF + n, acc[tm][tn][r]);
    }
  }
}

// ---------------- finalize: h += theta*feat, feat32 -> featT bf16 (transposed), re-zero ----------------
__global__ void finalize_hop(float* __restrict__ feat32, float* __restrict__ h,
                             unsigned short* __restrict__ featT,
                             const float* __restrict__ theta, int hop) {
  __shared__ float tile[32][33];
  int m0 = blockIdx.x * 32;
  int n0 = blockIdx.y * 32;
  int tx = threadIdx.x & 31, ty = threadIdx.x >> 5;
  float th = theta[hop];
#pragma unroll
  for (int r = 0; r < 4; ++r) {
    int mm = ty + r * 8;
    size_t idx = (size_t)(m0 + mm) * FF + n0 + tx;
    float v = feat32[idx];
    tile[mm][tx] = v;
    float hv = th * v;
    if (hop > 0) hv += h[idx];
    h[idx] = hv;
    if (hop < DD - 1) feat32[idx] = 0.0f;
  }
  if (hop < DD - 1) {
    __syncthreads();
#pragma unroll
    for (int r = 0; r < 4; ++r) {
      int nn = ty + r * 8;
      featT[(size_t)(n0 + nn) * NN + m0 + tx] = f2bf(tile[tx][nn]);
    }
  }
}

extern "C" void kernel_launch(void* const* d_in, const int* in_sizes, int n_in,
                              void* d_out, int out_size, void* d_ws, size_t ws_size,
                              hipStream_t stream) {
  const float* adj = (const float*)d_in[0];
  const float* in_feat = (const float*)d_in[1];
  const float* theta = (const float*)d_in[3];  // d_in[2] (lapl) unused by forward
  float* h = (float*)d_out;

  char* ws = (char*)d_ws;
  unsigned short* adjb = (unsigned short*)ws;                       // 128 MiB
  unsigned short* fTa = (unsigned short*)(ws + (size_t)NN * NN * 2);  // 2 MiB
  unsigned short* fTb = fTa + (size_t)FF * NN;                        // 2 MiB
  float* feat32 = (float*)(fTb + (size_t)FF * NN);                    // 4 MiB

  cvt_adj<<<(int)((size_t)NN * NN / (256 * 8)), 256, 0, stream>>>(adj, adjb);
  cvt_feat<<<dim3(NN / 32, FF / 32), 256, 0, stream>>>(in_feat, fTa);
  hipMemsetAsync(feat32, 0, (size_t)NN * FF * 4, stream);

  unsigned short* fin = fTa;
  unsigned short* fout = fTb;
  for (int hop = 0; hop < DD; ++hop) {
    gemm_hop<<<64 * KSPLIT, 256, 0, stream>>>(adjb, fin, feat32);
    finalize_hop<<<dim3(NN / 32, FF / 32), 256, 0, stream>>>(feat32, h, fout, theta, hop);
    unsigned short* tmp = fin; fin = fout; fout = tmp;
  }
}

// Round 2
// 664.112 us; speedup vs baseline: 1.0136x; 1.0136x over previous
//
#include <hip/hip_runtime.h>
#include <stdint.h>

#define NN 8192
#define FF 128
#define DD 4
#define BM 128
#define BN 128
#define BK 64
#define KSPLIT 16
#define KCHUNK (NN / KSPLIT)  // 512

typedef __attribute__((ext_vector_type(8))) short bf16x8;
typedef __attribute__((ext_vector_type(4))) float f32x4;

__device__ __forceinline__ unsigned short f2bf(float f) {
  uint32_t u = __float_as_uint(f);
  u += 0x7fffu + ((u >> 16) & 1u);  // round-to-nearest-even
  return (unsigned short)(u >> 16);
}

__device__ __forceinline__ void gld_lds16(const void* g, void* l) {
  auto gp = reinterpret_cast<const uint32_t __attribute__((address_space(1)))*>(
      reinterpret_cast<uintptr_t>(g));
  auto lp = reinterpret_cast<uint32_t __attribute__((address_space(3)))*>(
      reinterpret_cast<uintptr_t>(l));
  __builtin_amdgcn_global_load_lds(gp, lp, 16, 0, 0);
}

// ---------------- adj fp32 -> bf16 ----------------
__global__ void cvt_adj(const float* __restrict__ a, unsigned short* __restrict__ o) {
  size_t i = ((size_t)blockIdx.x * 256 + threadIdx.x) * 8;
  float4 v0 = *(const float4*)(a + i);
  float4 v1 = *(const float4*)(a + i + 4);
  union { unsigned short us[8]; uint4 v; } p;
  p.us[0] = f2bf(v0.x); p.us[1] = f2bf(v0.y); p.us[2] = f2bf(v0.z); p.us[3] = f2bf(v0.w);
  p.us[4] = f2bf(v1.x); p.us[5] = f2bf(v1.y); p.us[6] = f2bf(v1.z); p.us[7] = f2bf(v1.w);
  *(uint4*)(o + i) = p.v;
}

// ---------------- in_feat [NN][FF] fp32 -> featT [FF][NN] bf16 ----------------
__global__ void cvt_feat(const float* __restrict__ x, unsigned short* __restrict__ xT) {
  __shared__ float tile[32][33];
  int m0 = blockIdx.x * 32;
  int n0 = blockIdx.y * 32;
  int tx = threadIdx.x & 31, ty = threadIdx.x >> 5;
#pragma unroll
  for (int r = 0; r < 4; ++r) {
    int mm = ty + r * 8;
    tile[mm][tx] = x[(size_t)(m0 + mm) * FF + n0 + tx];
  }
  __syncthreads();
#pragma unroll
  for (int r = 0; r < 4; ++r) {
    int nn = ty + r * 8;
    xT[(size_t)(n0 + nn) * NN + m0 + tx] = f2bf(tile[tx][nn]);
  }
}

// ---------------- GEMM: parts[ks][m][n] = sum_{k in chunk ks} adj_bf[m][k] * featT[n][k] ----------------
__global__ __launch_bounds__(256, 4) void gemm_hop(
    const unsigned short* __restrict__ adjb,
    const unsigned short* __restrict__ featT,
    float* __restrict__ parts) {
  __shared__ unsigned short sA[BM * BK];  // 16 KB, XOR-swizzled chunks
  __shared__ unsigned short sB[BN * BK];  // 16 KB

  const int bx = blockIdx.x;
  const int mt = bx & 63;
  const int ks = bx >> 6;
  const int m0 = mt * BM;
  const int k0 = ks * KCHUNK;

  const int t = threadIdx.x;
  const int w = t >> 6;
  const int l = t & 63;

  // Staging: sA/sB are each 16 KB = 16 wave-instructions of 1 KB.
  // Stored chunk c of row r holds GLOBAL chunk c ^ (r&7) (conflict-free LDS
  // reads; LDS side stays linear for global_load_lds).
  uint32_t offA[4], offB[4];
  unsigned short* ldsA[4];
  unsigned short* ldsB[4];
#pragma unroll
  for (int j = 0; j < 4; ++j) {
    uint32_t obase = (uint32_t)w * 4096u + (uint32_t)j * 1024u;
    uint32_t o = obase + (uint32_t)l * 16u;
    uint32_t r = o >> 7;
    uint32_t c = (o >> 4) & 7u;
    uint32_t gc = c ^ (r & 7u);
    ldsA[j] = sA + (obase >> 1);
    ldsB[j] = sB + (obase >> 1);
    offA[j] = (uint32_t)(m0 + r) * (uint32_t)NN + (uint32_t)k0 + gc * 8u;
    offB[j] = r * (uint32_t)NN + (uint32_t)k0 + gc * 8u;
  }

  f32x4 acc[4][4];
#pragma unroll
  for (int i = 0; i < 4; ++i)
#pragma unroll
    for (int j = 0; j < 4; ++j) acc[i][j] = (f32x4){0.f, 0.f, 0.f, 0.f};

  const int wm = w >> 1;  // 2x2 wave grid, each wave 64x64
  const int wn = w & 1;
  const int lr = l & 15;
  const int lq = l >> 4;

  for (int kt = 0; kt < KCHUNK; kt += BK) {
#pragma unroll
    for (int j = 0; j < 4; ++j) gld_lds16(adjb + offA[j], ldsA[j]);
#pragma unroll
    for (int j = 0; j < 4; ++j) gld_lds16(featT + offB[j], ldsB[j]);
#pragma unroll
    for (int j = 0; j < 4; ++j) { offA[j] += BK; offB[j] += BK; }
    __syncthreads();
#pragma unroll
    for (int kk = 0; kk < 2; ++kk) {
      bf16x8 af[4], bfr[4];
#pragma unroll
      for (int tm = 0; tm < 4; ++tm) {
        int row = wm * 64 + tm * 16 + lr;
        int ch = (kk * 4 + lq) ^ (row & 7);
        af[tm] = *(const bf16x8*)(sA + row * BK + ch * 8);
      }
#pragma unroll
      for (int tn = 0; tn < 4; ++tn) {
        int row = wn * 64 + tn * 16 + lr;
        int ch = (kk * 4 + lq) ^ (row & 7);
        bfr[tn] = *(const bf16x8*)(sB + row * BK + ch * 8);
      }
#pragma unroll
      for (int tm = 0; tm < 4; ++tm)
#pragma unroll
        for (int tn = 0; tn < 4; ++tn)
          acc[tm][tn] = __builtin_amdgcn_mfma_f32_16x16x32_bf16(
              af[tm], bfr[tn], acc[tm][tn], 0, 0, 0);
    }
    __syncthreads();
  }

  // epilogue: plain streaming stores to this block's private partial tile
  float* pout = parts + (size_t)ks * NN * FF;
#pragma unroll
  for (int tm = 0; tm < 4; ++tm) {
#pragma unroll
    for (int tn = 0; tn < 4; ++tn) {
      int m = m0 + wm * 64 + tm * 16 + lq * 4;
      int n = wn * 64 + tn * 16 + lr;
#pragma unroll
      for (int r = 0; r < 4; ++r)
        pout[(size_t)(m + r) * FF + n] = acc[tm][tn][r];
    }
  }
}

// ---------------- finalize: feat = sum_s parts[s]; h += theta*feat; featT = bf16(feat^T) ----------------
__global__ void finalize_hop(const float* __restrict__ parts, float* __restrict__ h,
                             unsigned short* __restrict__ featT,
                             const float* __restrict__ theta, int hop) {
  __shared__ float tile[32][33];
  int m0 = blockIdx.x * 32;
  int n0 = blockIdx.y * 32;
  int tx = threadIdx.x & 31, ty = threadIdx.x >> 5;
  float th = theta[hop];
#pragma unroll
  for (int r = 0; r < 4; ++r) {
    int mm = ty + r * 8;
    size_t idx = (size_t)(m0 + mm) * FF + n0 + tx;
    float acc = 0.0f;
#pragma unroll
    for (int s = 0; s < KSPLIT; ++s) acc += parts[(size_t)s * NN * FF + idx];
    tile[mm][tx] = acc;
    float hv = th * acc;
    if (hop > 0) hv += h[idx];
    h[idx] = hv;
  }
  if (hop < DD - 1) {
    __syncthreads();
#pragma unroll
    for (int r = 0; r < 4; ++r) {
      int nn = ty + r * 8;
      featT[(size_t)(n0 + nn) * NN + m0 + tx] = f2bf(tile[tx][nn]);
    }
  }
}

extern "C" void kernel_launch(void* const* d_in, const int* in_sizes, int n_in,
                              void* d_out, int out_size, void* d_ws, size_t ws_size,
                              hipStream_t stream) {
  const float* adj = (const float*)d_in[0];
  const float* in_feat = (const float*)d_in[1];
  const float* theta = (const float*)d_in[3];  // d_in[2] (lapl) unused by forward
  float* h = (float*)d_out;

  char* ws = (char*)d_ws;
  unsigned short* adjb = (unsigned short*)ws;                         // 128 MiB
  unsigned short* fTa = (unsigned short*)(ws + (size_t)NN * NN * 2);  // 2 MiB
  unsigned short* fTb = fTa + (size_t)FF * NN;                        // 2 MiB
  float* parts = (float*)(fTb + (size_t)FF * NN);                     // 64 MiB

  cvt_adj<<<(int)((size_t)NN * NN / (256 * 8)), 256, 0, stream>>>(adj, adjb);
  cvt_feat<<<dim3(NN / 32, FF / 32), 256, 0, stream>>>(in_feat, fTa);

  unsigned short* fin = fTa;
  unsigned short* fout = fTb;
  for (int hop = 0; hop < DD; ++hop) {
    gemm_hop<<<64 * KSPLIT, 256, 0, stream>>>(adjb, fin, parts);
    finalize_hop<<<dim3(NN / 32, FF / 32), 256, 0, stream>>>(parts, h, fout, theta, hop);
    unsigned short* tmp = fin; fin = fout; fout = tmp;
  }
}